// Round 7
// baseline (204.540 us; speedup 1.0000x reference)
//
#include <hip/hip_runtime.h>

typedef unsigned short u16;
typedef short bf8_t __attribute__((ext_vector_type(8)));
typedef float f32x4 __attribute__((ext_vector_type(4)));

__device__ __forceinline__ u16 f2bf(float f) {
  unsigned u = __builtin_bit_cast(unsigned, f);
  unsigned r = (u + 0x7fffu + ((u >> 16) & 1u)) >> 16;
  return (u16)r;
}

__device__ __forceinline__ float b2f(u16 v) {
  unsigned u = ((unsigned)v) << 16;
  return __builtin_bit_cast(float, u);
}

__device__ __forceinline__ void gld16(const void* g, void* l) {
  __builtin_amdgcn_global_load_lds((const __attribute__((address_space(1))) unsigned int*)g,
                                   (__attribute__((address_space(3))) unsigned int*)l, 16, 0, 0);
}

#define MFMA(a, b, c) __builtin_amdgcn_mfma_f32_16x16x32_bf16((a), (b), (c), 0, 0, 0)

// ---------------- weight transpose: W fp32 [K][N] -> WT bf16 [N][K] ----------------
__global__ void wtrans_kernel(const float* __restrict__ W, u16* __restrict__ WT, int K, int N) {
  __shared__ float tile[32][33];
  const int n0 = blockIdx.x << 5, k0 = blockIdx.y << 5;
  const int tx = threadIdx.x, ty = threadIdx.y;  // (32, 8)
#pragma unroll
  for (int i = 0; i < 4; i++) {
    const int r = ty + (i << 3);
    tile[r][tx] = W[(size_t)(k0 + r) * N + n0 + tx];
  }
  __syncthreads();
#pragma unroll
  for (int i = 0; i < 4; i++) {
    const int r = ty + (i << 3);
    WT[(size_t)(n0 + r) * K + k0 + tx] = f2bf(tile[tx][r]);
  }
}

// ---------------- LayerNorm (768 cols) fp32 in -> bf16 out ----------------
__global__ void ln_kernel(const float* __restrict__ x, const float* __restrict__ g,
                          const float* __restrict__ bb, u16* __restrict__ o) {
  const int row = blockIdx.x, t = threadIdx.x;
  const float* xr = x + (size_t)row * 768;
  float v[3];
#pragma unroll
  for (int i = 0; i < 3; i++) v[i] = xr[t + (i << 8)];
  float s = v[0] + v[1] + v[2];
#pragma unroll
  for (int off = 1; off < 64; off <<= 1) s += __shfl_xor(s, off, 64);
  __shared__ float red[4];
  const int w = t >> 6;
  if ((t & 63) == 0) red[w] = s;
  __syncthreads();
  const float mu = (red[0] + red[1] + red[2] + red[3]) * (1.f / 768.f);
  float q = 0.f;
#pragma unroll
  for (int i = 0; i < 3; i++) {
    v[i] -= mu;
    q += v[i] * v[i];
  }
#pragma unroll
  for (int off = 1; off < 64; off <<= 1) q += __shfl_xor(q, off, 64);
  __syncthreads();
  if ((t & 63) == 0) red[w] = q;
  __syncthreads();
  const float var = (red[0] + red[1] + red[2] + red[3]) * (1.f / 768.f);
  const float rs = rsqrtf(var + 1e-5f);
#pragma unroll
  for (int i = 0; i < 3; i++) {
    const int idx = t + (i << 8);
    o[(size_t)row * 768 + idx] = f2bf(v[i] * rs * g[idx] + bb[idx]);
  }
}

// ---------------- GEMM: C[M,N] = A[M,K](bf16) @ BT[N,K](bf16)^T, epilogues ----------------
// EPI 0: +bias -> bf16; 1: +bias, gelu -> bf16; 2: +bias +res(fp32) -> fp32;
// EPI 3: raw fp32 partial (split-K; blockIdx.z selects K-chunk and partial buffer)
// 3-buffer depth-2 pipelined K-loop: raw s_barrier + counted vmcnt(4) (stage t+1 stays in
// flight across the barrier), stage t+2 issued after the barrier, compute t. Buffer written
// at iter t is the one read at t-1; barrier at t follows all waves' t-1 compute -> safe.
template <int EPI>
__global__ void gemm_kernel(const u16* __restrict__ A, const u16* __restrict__ BT,
                            const float* __restrict__ bias, const float* __restrict__ res,
                            void* __restrict__ outp, int M, int N, int K, int kLen) {
  __shared__ __align__(16) u16 As[3][128 * 32];
  __shared__ __align__(16) u16 Bs[3][128 * 32];
  const int m0 = blockIdx.y << 7, n0 = blockIdx.x << 7;
  const int kOff = blockIdx.z * kLen;
  const int tid = threadIdx.x, lane = tid & 63, w = tid >> 6;
  const int wr = w >> 1, wc = w & 1;
  const int l16 = lane & 15, kg = lane >> 4;
  f32x4 acc[4][4];
  const f32x4 fz = {0.f, 0.f, 0.f, 0.f};
#pragma unroll
  for (int i = 0; i < 4; i++)
#pragma unroll
    for (int j = 0; j < 4; j++) acc[i][j] = fz;

  const int c1 = (w << 6) + lane;  // chunk ids (16B chunks), 512 per tile
  const int r1 = c1 >> 2, ko1 = (c1 & 3) << 3;
  const int c2 = c1 + 256;
  const int r2 = c2 >> 2, ko2 = (c2 & 3) << 3;
  const int lb1 = (c1 - lane) * 8, lb2 = (c2 - lane) * 8;  // wave-uniform LDS bases

  const u16* Arow1 = A + (size_t)(m0 + r1) * K + kOff + ko1;
  const u16* Arow2 = A + (size_t)(m0 + r2) * K + kOff + ko2;
  const u16* Brow1 = BT + (size_t)(n0 + r1) * K + kOff + ko1;
  const u16* Brow2 = BT + (size_t)(n0 + r2) * K + kOff + ko2;

#define GSTAGE(buf_, kt_)                    \
  do {                                       \
    const int k0_ = (kt_) << 5;              \
    gld16(Arow1 + k0_, As[buf_] + lb1);      \
    gld16(Arow2 + k0_, As[buf_] + lb2);      \
    gld16(Brow1 + k0_, Bs[buf_] + lb1);      \
    gld16(Brow2 + k0_, Bs[buf_] + lb2);      \
  } while (0)

  const int nkt = kLen >> 5;
  GSTAGE(0, 0);
  if (nkt > 1) GSTAGE(1, 1);
  int cur = 0, pre = 2;  // pre = (kt+2)%3
  for (int kt = 0; kt < nkt; kt++) {
    if (kt + 1 < nkt) {
      asm volatile("s_waitcnt vmcnt(4)" ::: "memory");  // stage(kt) landed; kt+1 in flight
    } else {
      asm volatile("s_waitcnt vmcnt(0)" ::: "memory");  // tail: drain last stage
    }
    __builtin_amdgcn_s_barrier();
    __builtin_amdgcn_sched_barrier(0);
    if (kt + 2 < nkt) GSTAGE(pre, kt + 2);
    bf8_t af[4], bfr[4];
#pragma unroll
    for (int mf = 0; mf < 4; mf++)
      af[mf] = *(const bf8_t*)&As[cur][((wr << 6) + (mf << 4) + l16) * 32 + (kg << 3)];
#pragma unroll
    for (int nf = 0; nf < 4; nf++)
      bfr[nf] = *(const bf8_t*)&Bs[cur][((wc << 6) + (nf << 4) + l16) * 32 + (kg << 3)];
#pragma unroll
    for (int mf = 0; mf < 4; mf++)
#pragma unroll
      for (int nf = 0; nf < 4; nf++) acc[mf][nf] = MFMA(af[mf], bfr[nf], acc[mf][nf]);
    cur = (cur == 2) ? 0 : cur + 1;
    pre = (pre == 2) ? 0 : pre + 1;
  }
#undef GSTAGE
  float* pout = (float*)outp + (size_t)blockIdx.z * M * N;  // EPI 3 partial buffer
#pragma unroll
  for (int mf = 0; mf < 4; mf++) {
#pragma unroll
    for (int nf = 0; nf < 4; nf++) {
      const int col = n0 + (wc << 6) + (nf << 4) + l16;
      const float bv = (EPI == 3) ? 0.f : bias[col];
#pragma unroll
      for (int j = 0; j < 4; j++) {
        const int row = m0 + (wr << 6) + (mf << 4) + (kg << 2) + j;
        float v = acc[mf][nf][j] + bv;
        if constexpr (EPI == 0) {
          ((u16*)outp)[(size_t)row * N + col] = f2bf(v);
        } else if constexpr (EPI == 1) {
          const float u = 0.7978845608f * (v + 0.044715f * v * v * v);
          const float e = __expf(2.f * u);
          const float th = 1.f - 2.f / (e + 1.f);
          ((u16*)outp)[(size_t)row * N + col] = f2bf(0.5f * v * (1.f + th));
        } else if constexpr (EPI == 2) {
          v += res[(size_t)row * N + col];
          ((float*)outp)[(size_t)row * N + col] = v;
        } else {
          pout[(size_t)row * N + col] = v;
        }
      }
    }
  }
}

// ---------------- split-K reduce: out = sum(parts) + bias + res (M=4096, N=768 fp32) ----------------
__global__ void reduce_kernel(const float* __restrict__ parts, const float* __restrict__ bias,
                              const float* __restrict__ res, float* __restrict__ out, int ns) {
  const int row = blockIdx.x, col = threadIdx.x << 2;  // 192 threads * 4
  const size_t base = (size_t)row * 768 + col;
  f32x4 a = *(const f32x4*)(parts + base);
  for (int s = 1; s < ns; s++) a += *(const f32x4*)(parts + (size_t)s * 4096 * 768 + base);
  const f32x4 bv = *(const f32x4*)(bias + col);
  const f32x4 rv = *(const f32x4*)(res + base);
  *(f32x4*)(out + base) = a + bv + rv;
}

// ---------------- flash attention, causal, hd=64: split-KV chunked (flash-decode) ----------------
template <bool SPLIT>
__global__ __launch_bounds__(256, 3) void attn_kernel(const u16* __restrict__ qkv,
                                                      u16* __restrict__ part_o,
                                                      float* __restrict__ partML,
                                                      u16* __restrict__ y) {
  __shared__ __align__(16) u16 Ks[2][64 * 64];
  __shared__ __align__(16) u16 Vt[2][64 * 64];
  __shared__ __align__(16) u16 Ps[4][16 * 72];
  int qt, c, t0, t1;
  if constexpr (SPLIT) {
    const int cid = 39 - (int)blockIdx.x;  // heavy groups first
    int g = 0, base = 0;
    while (cid >= base + 4 * (g + 1)) {
      base += 4 * (g + 1);
      g++;
    }
    const int r = cid - base;
    qt = (g << 2) + r / (g + 1);
    c = r % (g + 1);
    t0 = c << 2;
    t1 = min(t0 + 4, qt + 1);
  } else {
    qt = (int)gridDim.x - 1 - (int)blockIdx.x;
    c = 0;
    t0 = 0;
    t1 = qt + 1;
  }
  const int bh = blockIdx.y;
  const int b = bh / 12, h = bh - b * 12;
  const size_t brow = (size_t)b << 10;
  const int q0 = qt << 6;
  const int tid = threadIdx.x, lane = tid & 63, w = tid >> 6;
  const int l16 = lane & 15, kg = lane >> 4;

  const int c1 = tid, c2 = tid + 256;  // 512 chunks = 64 rows * 8
  const int row1 = c1 >> 3, cc1 = c1 & 7;
  const int row2 = c2 >> 3, cc2 = c2 & 7;
  const int sw1 = ((cc1 ^ (row1 & 7)) << 3);  // K pre-swizzled source elem offset
  const int sw2 = ((cc2 ^ (row2 & 7)) << 3);
  // sigma = 3-bit bit-reverse for V store swizzle
  const int sg1 = ((cc1 & 1) << 2) | (cc1 & 2) | ((cc1 >> 2) & 1);
  const int sg2 = ((cc2 & 1) << 2) | (cc2 & 2) | ((cc2 >> 2) & 1);
  const int vcol1 = row1 ^ (sg1 << 3), d01 = cc1 << 3;
  const int vcol2 = row2 ^ (sg2 << 3), d02 = cc2 << 3;

  const int cbK = 768 + (h << 6), cbV = 1536 + (h << 6);

  // Q fragments direct from global (one-time)
  const u16* Qbase = qkv + (brow + q0 + (w << 4) + l16) * 2304 + (h << 6) + (kg << 3);
  const bf8_t qf0 = *(const bf8_t*)(Qbase);
  const bf8_t qf1 = *(const bf8_t*)(Qbase + 32);

  // prologue: stage K(t0); load V(t0) rows into regs
  gld16(qkv + (brow + (t0 << 6) + row1) * 2304 + cbK + sw1, Ks[t0 & 1] + (size_t)(c1 - lane) * 8);
  gld16(qkv + (brow + (t0 << 6) + row2) * 2304 + cbK + sw2, Ks[t0 & 1] + (size_t)(c2 - lane) * 8);
  bf8_t v1 = *(const bf8_t*)(qkv + (brow + (t0 << 6) + row1) * 2304 + cbV + (cc1 << 3));
  bf8_t v2 = *(const bf8_t*)(qkv + (brow + (t0 << 6) + row2) * 2304 + cbV + (cc2 << 3));

  f32x4 oacc[4];
  const f32x4 fz = {0.f, 0.f, 0.f, 0.f};
#pragma unroll
  for (int dg = 0; dg < 4; dg++) oacc[dg] = fz;
  float mrun[4], lrun[4];
#pragma unroll
  for (int j = 0; j < 4; j++) {
    mrun[j] = -1e30f;
    lrun[j] = 0.f;
  }

  for (int kt = t0; kt < t1; kt++) {
    const int cur = kt & 1;
    u16* Vc = Vt[cur];
    // write staged V regs -> swizzled transposed LDS (conflict-free)
#pragma unroll
    for (int i = 0; i < 8; i++) Vc[(d01 + i) * 64 + vcol1] = (u16)v1[i];
#pragma unroll
    for (int i = 0; i < 8; i++) Vc[(d02 + i) * 64 + vcol2] = (u16)v2[i];
    __syncthreads();  // drains K(kt) gld16, publishes Vt(kt)

    if (kt + 1 < t1) {  // issue next tile's staging; completes under this tile's compute
      const int nr = (kt + 1) << 6;
      gld16(qkv + (brow + nr + row1) * 2304 + cbK + sw1, Ks[cur ^ 1] + (size_t)(c1 - lane) * 8);
      gld16(qkv + (brow + nr + row2) * 2304 + cbK + sw2, Ks[cur ^ 1] + (size_t)(c2 - lane) * 8);
      v1 = *(const bf8_t*)(qkv + (brow + nr + row1) * 2304 + cbV + (cc1 << 3));
      v2 = *(const bf8_t*)(qkv + (brow + nr + row2) * 2304 + cbV + (cc2 << 3));
    }

    const u16* Kc = Ks[cur];
    // QK^T -> sv[g][j]
    float sv[4][4];
#pragma unroll
    for (int g = 0; g < 4; g++) {
      const int key = (g << 4) + l16;
      const int ch0 = kg ^ (key & 7);
      const int ch1 = (kg + 4) ^ (key & 7);
      f32x4 z = fz;
      z = MFMA(qf0, *(const bf8_t*)&Kc[key * 64 + (ch0 << 3)], z);
      z = MFMA(qf1, *(const bf8_t*)&Kc[key * 64 + (ch1 << 3)], z);
      const int gkey = (kt << 6) + key;
#pragma unroll
      for (int j = 0; j < 4; j++) {
        const int grow = q0 + (w << 4) + (kg << 2) + j;
        sv[g][j] = (gkey <= grow) ? z[j] * 0.125f : -1e30f;
      }
    }
    // online softmax (16-lane row groups)
    float tm[4];
#pragma unroll
    for (int j = 0; j < 4; j++)
      tm[j] = fmaxf(fmaxf(sv[0][j], sv[1][j]), fmaxf(sv[2][j], sv[3][j]));
#pragma unroll
    for (int o = 1; o < 16; o <<= 1)
#pragma unroll
      for (int j = 0; j < 4; j++) tm[j] = fmaxf(tm[j], __shfl_xor(tm[j], o, 64));
    float corr[4], tsum[4];
#pragma unroll
    for (int j = 0; j < 4; j++) {
      const float mn = fmaxf(mrun[j], tm[j]);
      corr[j] = __expf(mrun[j] - mn);
      mrun[j] = mn;
      tsum[j] = 0.f;
    }
#pragma unroll
    for (int g = 0; g < 4; g++)
#pragma unroll
      for (int j = 0; j < 4; j++) {
        const float p = __expf(sv[g][j] - mrun[j]);
        sv[g][j] = p;
        tsum[j] += p;
      }
#pragma unroll
    for (int o = 1; o < 16; o <<= 1)
#pragma unroll
      for (int j = 0; j < 4; j++) tsum[j] += __shfl_xor(tsum[j], o, 64);
#pragma unroll
    for (int j = 0; j < 4; j++) lrun[j] = lrun[j] * corr[j] + tsum[j];
#pragma unroll
    for (int dg = 0; dg < 4; dg++)
#pragma unroll
      for (int j = 0; j < 4; j++) oacc[dg][j] *= corr[j];
    // P -> LDS bf16 (C-layout -> A-layout relay, per-wave)
#pragma unroll
    for (int g = 0; g < 4; g++)
#pragma unroll
      for (int j = 0; j < 4; j++)
        Ps[w][((kg << 2) + j) * 72 + (g << 4) + l16] = f2bf(sv[g][j]);
    const bf8_t pf0 = *(const bf8_t*)&Ps[w][l16 * 72 + (kg << 3)];
    const bf8_t pf1 = *(const bf8_t*)&Ps[w][l16 * 72 + (kg << 3) + 32];
    // PV from sigma-swizzled Vt (conflict-free b128 reads)
#pragma unroll
    for (int dg = 0; dg < 4; dg++) {
      const int sgr = (((l16 >> 3) & 1) << 2) | ((dg & 1) << 1) | (dg >> 1);
      const int d = (dg << 4) + l16;
      oacc[dg] = MFMA(pf0, *(const bf8_t*)&Vc[d * 64 + ((kg ^ sgr) << 3)], oacc[dg]);
      oacc[dg] = MFMA(pf1, *(const bf8_t*)&Vc[d * 64 + (((4 + kg) ^ sgr) << 3)], oacc[dg]);
    }
  }

  float inv[4];
#pragma unroll
  for (int j = 0; j < 4; j++) inv[j] = 1.f / lrun[j];
  if constexpr (SPLIT) {
    const int slot = (((bh << 4) + qt) << 2) + c;
    u16* po = part_o + (size_t)slot * 4096;
#pragma unroll
    for (int dg = 0; dg < 4; dg++)
#pragma unroll
      for (int j = 0; j < 4; j++)
        po[((w << 4) + (kg << 2) + j) * 64 + (dg << 4) + l16] = f2bf(oacc[dg][j] * inv[j]);
    if (l16 == 0) {
#pragma unroll
      for (int j = 0; j < 4; j++) {
        const int rr = (w << 4) + (kg << 2) + j;
        partML[(size_t)slot * 128 + rr * 2] = mrun[j];
        partML[(size_t)slot * 128 + rr * 2 + 1] = lrun[j];
      }
    }
  } else {
#pragma unroll
    for (int dg = 0; dg < 4; dg++)
#pragma unroll
      for (int j = 0; j < 4; j++) {
        const size_t grow = brow + q0 + (w << 4) + (kg << 2) + j;
        y[grow * 768 + (h << 6) + (dg << 4) + l16] = f2bf(oacc[dg][j] * inv[j]);
      }
  }
}

// ---------------- combine: merge <=4 normalized chunk partials per (qt, bh) ----------------
__global__ void attn_combine(const u16* __restrict__ part_o, const float* __restrict__ partML,
                             u16* __restrict__ y) {
  const int qt = blockIdx.x, bh = blockIdx.y;
  const int nc = (qt >> 2) + 1;
  const int tid = threadIdx.x;          // 256
  const int r = tid >> 2, cg = tid & 3; // row, 16-col group
  const int b = bh / 12, h = bh - b * 12;
  const int slot0 = ((bh << 4) + qt) << 2;
  float mv0 = -1e30f, mv1 = -1e30f, mv2 = -1e30f, mv3 = -1e30f;
  float lv0 = 0.f, lv1 = 0.f, lv2 = 0.f, lv3 = 0.f;
  mv0 = partML[(size_t)(slot0 + 0) * 128 + r * 2];
  lv0 = partML[(size_t)(slot0 + 0) * 128 + r * 2 + 1];
  if (nc > 1) {
    mv1 = partML[(size_t)(slot0 + 1) * 128 + r * 2];
    lv1 = partML[(size_t)(slot0 + 1) * 128 + r * 2 + 1];
  }
  if (nc > 2) {
    mv2 = partML[(size_t)(slot0 + 2) * 128 + r * 2];
    lv2 = partML[(size_t)(slot0 + 2) * 128 + r * 2 + 1];
  }
  if (nc > 3) {
    mv3 = partML[(size_t)(slot0 + 3) * 128 + r * 2];
    lv3 = partML[(size_t)(slot0 + 3) * 128 + r * 2 + 1];
  }
  const float M = fmaxf(fmaxf(mv0, mv1), fmaxf(mv2, mv3));
  const float w0 = __expf(mv0 - M) * lv0;
  const float w1 = (nc > 1) ? __expf(mv1 - M) * lv1 : 0.f;
  const float w2 = (nc > 2) ? __expf(mv2 - M) * lv2 : 0.f;
  const float w3 = (nc > 3) ? __expf(mv3 - M) * lv3 : 0.f;
  const float invL = 1.f / (w0 + w1 + w2 + w3);
  float acc[16];
#pragma unroll
  for (int i = 0; i < 16; i++) acc[i] = 0.f;
#pragma unroll
  for (int cc = 0; cc < 4; cc++) {
    if (cc < nc) {
      const float wv = (cc == 0) ? w0 : (cc == 1) ? w1 : (cc == 2) ? w2 : w3;
      const bf8_t* op = (const bf8_t*)(part_o + (size_t)(slot0 + cc) * 4096 + r * 64 + (cg << 4));
      const bf8_t o0 = op[0], o1 = op[1];
#pragma unroll
      for (int i = 0; i < 8; i++) {
        acc[i] += wv * b2f((u16)o0[i]);
        acc[8 + i] += wv * b2f((u16)o1[i]);
      }
    }
  }
  u16* yp = y + ((size_t)(b << 10) + (qt << 6) + r) * 768 + (h << 6) + (cg << 4);
#pragma unroll
  for (int i = 0; i < 16; i++) yp[i] = f2bf(acc[i] * invL);
}

// ---------------- launch ----------------
extern "C" void kernel_launch(void* const* d_in, const int* in_sizes, int n_in,
                              void* d_out, int out_size, void* d_ws, size_t ws_size,
                              hipStream_t stream) {
  const float* x = (const float*)d_in[0];
  const float* ln1_g = (const float*)d_in[1];
  const float* ln1_b = (const float*)d_in[2];
  const float* ln2_g = (const float*)d_in[3];
  const float* ln2_b = (const float*)d_in[4];
  const float* w_attn = (const float*)d_in[5];
  const float* b_attn = (const float*)d_in[6];
  const float* w_proj = (const float*)d_in[7];
  const float* b_proj = (const float*)d_in[8];
  const float* w_fc = (const float*)d_in[9];
  const float* b_fc = (const float*)d_in[10];
  const float* w_mlp = (const float*)d_in[11];
  const float* b_mlp = (const float*)d_in[12];
  float* out = (float*)d_out;

  char* ws = (char*)d_ws;
  u16* wqkvT = (u16*)(ws + 0);
  u16* wprojT = (u16*)(ws + 3538944);
  u16* wfcT = (u16*)(ws + 4718592);
  u16* wmlpT = (u16*)(ws + 9437184);
  u16* xn = (u16*)(ws + 14155776);
  u16* qkv = (u16*)(ws + 20447232);
  u16* hbuf = (u16*)(ws + 20447232);  // reuses qkv (dead after attn)
  u16* yb = (u16*)(ws + 45613056);
  float* x1 = (float*)(ws + 51904512);
  float* parts = (float*)(ws + 64487424);   // split-K partials (proj/mlp), 12.58MB each
  u16* part_o = (u16*)(ws + 64487424);      // attn chunk partials (alias; attn-time only)
  float* partML = (float*)(ws + 89653248);  // 3072 slots * 128 floats

  const size_t PSZ = (size_t)4096 * 768 * 4;
  const int nsMlp = (ws_size >= 64487424 + 4 * PSZ) ? 4 : (ws_size >= 64487424 + 2 * PSZ ? 2 : 1);
  const int nsProj = (ws_size >= 64487424 + 2 * PSZ) ? 2 : 1;
  const bool useSplit = ws_size >= 91226112;

  const dim3 wtb(32, 8);
  wtrans_kernel<<<dim3(2304 / 32, 768 / 32), wtb, 0, stream>>>(w_attn, wqkvT, 768, 2304);
  wtrans_kernel<<<dim3(768 / 32, 768 / 32), wtb, 0, stream>>>(w_proj, wprojT, 768, 768);
  wtrans_kernel<<<dim3(3072 / 32, 768 / 32), wtb, 0, stream>>>(w_fc, wfcT, 768, 3072);
  wtrans_kernel<<<dim3(768 / 32, 3072 / 32), wtb, 0, stream>>>(w_mlp, wmlpT, 3072, 768);

  ln_kernel<<<4096, 256, 0, stream>>>(x, ln1_g, ln1_b, xn);
  gemm_kernel<0><<<dim3(18, 32), 256, 0, stream>>>(xn, wqkvT, b_attn, nullptr, qkv,
                                                   4096, 2304, 768, 768);
  if (useSplit) {
    attn_kernel<true><<<dim3(40, 48), 256, 0, stream>>>(qkv, part_o, partML, yb);
    attn_combine<<<dim3(16, 48), 256, 0, stream>>>(part_o, partML, yb);
  } else {
    attn_kernel<false><<<dim3(16, 48), 256, 0, stream>>>(qkv, part_o, partML, yb);
  }

  if (nsProj == 2) {
    gemm_kernel<3><<<dim3(6, 32, 2), 256, 0, stream>>>(yb, wprojT, nullptr, nullptr, parts,
                                                       4096, 768, 768, 384);
    reduce_kernel<<<4096, 192, 0, stream>>>(parts, b_proj, x, x1, 2);
  } else {
    gemm_kernel<2><<<dim3(6, 32), 256, 0, stream>>>(yb, wprojT, b_proj, x, x1,
                                                    4096, 768, 768, 768);
  }

  ln_kernel<<<4096, 256, 0, stream>>>(x1, ln2_g, ln2_b, xn);
  gemm_kernel<1><<<dim3(24, 32), 256, 0, stream>>>(xn, wfcT, b_fc, nullptr, hbuf,
                                                   4096, 3072, 768, 768);

  if (nsMlp > 1) {
    gemm_kernel<3><<<dim3(6, 32, nsMlp), 256, 0, stream>>>(hbuf, wmlpT, nullptr, nullptr, parts,
                                                           4096, 768, 3072, 3072 / nsMlp);
    reduce_kernel<<<4096, 192, 0, stream>>>(parts, b_mlp, x1, out, nsMlp);
  } else {
    gemm_kernel<2><<<dim3(6, 32), 256, 0, stream>>>(hbuf, wmlpT, b_mlp, x1, out,
                                                    4096, 768, 3072, 3072);
  }
}

// Round 8
// 200.668 us; speedup vs baseline: 1.0193x; 1.0193x over previous
//
#include <hip/hip_runtime.h>

typedef unsigned short u16;
typedef short bf8_t __attribute__((ext_vector_type(8)));
typedef float f32x4 __attribute__((ext_vector_type(4)));

__device__ __forceinline__ u16 f2bf(float f) {
  unsigned u = __builtin_bit_cast(unsigned, f);
  unsigned r = (u + 0x7fffu + ((u >> 16) & 1u)) >> 16;
  return (u16)r;
}

__device__ __forceinline__ float b2f(u16 v) {
  unsigned u = ((unsigned)v) << 16;
  return __builtin_bit_cast(float, u);
}

__device__ __forceinline__ void gld16(const void* g, void* l) {
  __builtin_amdgcn_global_load_lds((const __attribute__((address_space(1))) unsigned int*)g,
                                   (__attribute__((address_space(3))) unsigned int*)l, 16, 0, 0);
}

#define MFMA(a, b, c) __builtin_amdgcn_mfma_f32_16x16x32_bf16((a), (b), (c), 0, 0, 0)

// ---------------- weight transpose: W fp32 [K][N] -> WT bf16 [N][K] ----------------
__global__ void wtrans_kernel(const float* __restrict__ W, u16* __restrict__ WT, int K, int N) {
  __shared__ float tile[32][33];
  const int n0 = blockIdx.x << 5, k0 = blockIdx.y << 5;
  const int tx = threadIdx.x, ty = threadIdx.y;  // (32, 8)
#pragma unroll
  for (int i = 0; i < 4; i++) {
    const int r = ty + (i << 3);
    tile[r][tx] = W[(size_t)(k0 + r) * N + n0 + tx];
  }
  __syncthreads();
#pragma unroll
  for (int i = 0; i < 4; i++) {
    const int r = ty + (i << 3);
    WT[(size_t)(n0 + r) * K + k0 + tx] = f2bf(tile[tx][r]);
  }
}

// ---------------- LayerNorm (768 cols) fp32 in -> bf16 out ----------------
__global__ void ln_kernel(const float* __restrict__ x, const float* __restrict__ g,
                          const float* __restrict__ bb, u16* __restrict__ o) {
  const int row = blockIdx.x, t = threadIdx.x;
  const float* xr = x + (size_t)row * 768;
  float v[3];
#pragma unroll
  for (int i = 0; i < 3; i++) v[i] = xr[t + (i << 8)];
  float s = v[0] + v[1] + v[2];
#pragma unroll
  for (int off = 1; off < 64; off <<= 1) s += __shfl_xor(s, off, 64);
  __shared__ float red[4];
  const int w = t >> 6;
  if ((t & 63) == 0) red[w] = s;
  __syncthreads();
  const float mu = (red[0] + red[1] + red[2] + red[3]) * (1.f / 768.f);
  float q = 0.f;
#pragma unroll
  for (int i = 0; i < 3; i++) {
    v[i] -= mu;
    q += v[i] * v[i];
  }
#pragma unroll
  for (int off = 1; off < 64; off <<= 1) q += __shfl_xor(q, off, 64);
  __syncthreads();
  if ((t & 63) == 0) red[w] = q;
  __syncthreads();
  const float var = (red[0] + red[1] + red[2] + red[3]) * (1.f / 768.f);
  const float rs = rsqrtf(var + 1e-5f);
#pragma unroll
  for (int i = 0; i < 3; i++) {
    const int idx = t + (i << 8);
    o[(size_t)row * 768 + idx] = f2bf(v[i] * rs * g[idx] + bb[idx]);
  }
}

// ---------------- GEMM: C[M,N] = A[M,K](bf16) @ BT[N,K](bf16)^T, epilogues ----------------
// EPI 0: +bias -> bf16; 1: +bias, gelu -> bf16; 2: +bias +res(fp32) -> fp32;
// EPI 3: raw fp32 partial (split-K; blockIdx.z selects K-chunk and partial buffer)
// STATIC 3-buffer depth-2 pipeline: six named LDS arrays + triple-unrolled K-loop so every
// ds_read/DMA base is a compile-time-distinct object -> compiler can prove no alias with the
// in-flight global_load_lds and must NOT insert vmcnt(0) before fragment reads (m201 pattern).
// Counted vmcnt(4) keeps the next stage in flight across the barrier. nkt % 3 == 0 required
// (all call sites: kLen/32 in {12,24,48,96}).
template <int EPI>
__global__ void gemm_kernel(const u16* __restrict__ A, const u16* __restrict__ BT,
                            const float* __restrict__ bias, const float* __restrict__ res,
                            void* __restrict__ outp, int M, int N, int K, int kLen) {
  __shared__ __align__(16) u16 As0[128 * 32], As1[128 * 32], As2[128 * 32];
  __shared__ __align__(16) u16 Bs0[128 * 32], Bs1[128 * 32], Bs2[128 * 32];
  const int m0 = blockIdx.y << 7, n0 = blockIdx.x << 7;
  const int kOff = blockIdx.z * kLen;
  const int tid = threadIdx.x, lane = tid & 63, w = tid >> 6;
  const int wr = w >> 1, wc = w & 1;
  const int l16 = lane & 15, kg = lane >> 4;
  f32x4 acc[4][4];
  const f32x4 fz = {0.f, 0.f, 0.f, 0.f};
#pragma unroll
  for (int i = 0; i < 4; i++)
#pragma unroll
    for (int j = 0; j < 4; j++) acc[i][j] = fz;

  const int c1 = (w << 6) + lane;  // chunk ids (16B chunks), 512 per tile
  const int r1 = c1 >> 2, ko1 = (c1 & 3) << 3;
  const int c2 = c1 + 256;
  const int r2 = c2 >> 2, ko2 = (c2 & 3) << 3;
  const int lb1 = (c1 - lane) * 8, lb2 = (c2 - lane) * 8;  // wave-uniform LDS bases

  const u16* Arow1 = A + (size_t)(m0 + r1) * K + kOff + ko1;
  const u16* Arow2 = A + (size_t)(m0 + r2) * K + kOff + ko2;
  const u16* Brow1 = BT + (size_t)(n0 + r1) * K + kOff + ko1;
  const u16* Brow2 = BT + (size_t)(n0 + r2) * K + kOff + ko2;

#define GSTAGE(BUF_, kt_)                   \
  do {                                      \
    const int k0_ = (kt_) << 5;             \
    gld16(Arow1 + k0_, As##BUF_ + lb1);     \
    gld16(Arow2 + k0_, As##BUF_ + lb2);     \
    gld16(Brow1 + k0_, Bs##BUF_ + lb1);     \
    gld16(Brow2 + k0_, Bs##BUF_ + lb2);     \
  } while (0)

#define KSTEP(CUR_, PRE_, kt_)                                                                 \
  do {                                                                                         \
    if ((kt_) + 1 < nkt)                                                                       \
      asm volatile("s_waitcnt vmcnt(4)" ::: "memory"); /* stage(kt) landed; kt+1 in flight */  \
    else                                                                                       \
      asm volatile("s_waitcnt vmcnt(0)" ::: "memory"); /* tail: drain last stage */            \
    __builtin_amdgcn_s_barrier();                                                              \
    __builtin_amdgcn_sched_barrier(0);                                                         \
    if ((kt_) + 2 < nkt) GSTAGE(PRE_, (kt_) + 2);                                              \
    bf8_t af_[4], bf_[4];                                                                      \
    _Pragma("unroll") for (int mf_ = 0; mf_ < 4; mf_++) af_[mf_] =                             \
        *(const bf8_t*)&As##CUR_[((wr << 6) + (mf_ << 4) + l16) * 32 + (kg << 3)];             \
    _Pragma("unroll") for (int nf_ = 0; nf_ < 4; nf_++) bf_[nf_] =                             \
        *(const bf8_t*)&Bs##CUR_[((wc << 6) + (nf_ << 4) + l16) * 32 + (kg << 3)];             \
    _Pragma("unroll") for (int mf_ = 0; mf_ < 4; mf_++)                                        \
        _Pragma("unroll") for (int nf_ = 0; nf_ < 4; nf_++)                                    \
            acc[mf_][nf_] = MFMA(af_[mf_], bf_[nf_], acc[mf_][nf_]);                           \
  } while (0)

  const int nkt = kLen >> 5;  // in {12,24,48,96}: always >=3 and %3==0
  GSTAGE(0, 0);
  GSTAGE(1, 1);
  for (int kt = 0; kt < nkt; kt += 3) {
    KSTEP(0, 2, kt);
    KSTEP(1, 0, kt + 1);
    KSTEP(2, 1, kt + 2);
  }
#undef GSTAGE
#undef KSTEP
  float* pout = (float*)outp + (size_t)blockIdx.z * M * N;  // EPI 3 partial buffer
#pragma unroll
  for (int mf = 0; mf < 4; mf++) {
#pragma unroll
    for (int nf = 0; nf < 4; nf++) {
      const int col = n0 + (wc << 6) + (nf << 4) + l16;
      const float bv = (EPI == 3) ? 0.f : bias[col];
#pragma unroll
      for (int j = 0; j < 4; j++) {
        const int row = m0 + (wr << 6) + (mf << 4) + (kg << 2) + j;
        float v = acc[mf][nf][j] + bv;
        if constexpr (EPI == 0) {
          ((u16*)outp)[(size_t)row * N + col] = f2bf(v);
        } else if constexpr (EPI == 1) {
          const float u = 0.7978845608f * (v + 0.044715f * v * v * v);
          const float e = __expf(2.f * u);
          const float th = 1.f - 2.f / (e + 1.f);
          ((u16*)outp)[(size_t)row * N + col] = f2bf(0.5f * v * (1.f + th));
        } else if constexpr (EPI == 2) {
          v += res[(size_t)row * N + col];
          ((float*)outp)[(size_t)row * N + col] = v;
        } else {
          pout[(size_t)row * N + col] = v;
        }
      }
    }
  }
}

// ---------------- split-K reduce: out = sum(parts) + bias + res (M=4096, N=768 fp32) ----------------
__global__ void reduce_kernel(const float* __restrict__ parts, const float* __restrict__ bias,
                              const float* __restrict__ res, float* __restrict__ out, int ns) {
  const int row = blockIdx.x, col = threadIdx.x << 2;  // 192 threads * 4
  const size_t base = (size_t)row * 768 + col;
  f32x4 a = *(const f32x4*)(parts + base);
  for (int s = 1; s < ns; s++) a += *(const f32x4*)(parts + (size_t)s * 4096 * 768 + base);
  const f32x4 bv = *(const f32x4*)(bias + col);
  const f32x4 rv = *(const f32x4*)(res + base);
  *(f32x4*)(out + base) = a + bv + rv;
}

// ---------------- flash attention, causal, hd=64: split-KV chunked (flash-decode) ----------------
template <bool SPLIT>
__global__ __launch_bounds__(256, 3) void attn_kernel(const u16* __restrict__ qkv,
                                                      u16* __restrict__ part_o,
                                                      float* __restrict__ partML,
                                                      u16* __restrict__ y) {
  __shared__ __align__(16) u16 Ks[2][64 * 64];
  __shared__ __align__(16) u16 Vt[2][64 * 64];
  __shared__ __align__(16) u16 Ps[4][16 * 72];
  int qt, c, t0, t1;
  if constexpr (SPLIT) {
    const int cid = 39 - (int)blockIdx.x;  // heavy groups first
    int g = 0, base = 0;
    while (cid >= base + 4 * (g + 1)) {
      base += 4 * (g + 1);
      g++;
    }
    const int r = cid - base;
    qt = (g << 2) + r / (g + 1);
    c = r % (g + 1);
    t0 = c << 2;
    t1 = min(t0 + 4, qt + 1);
  } else {
    qt = (int)gridDim.x - 1 - (int)blockIdx.x;
    c = 0;
    t0 = 0;
    t1 = qt + 1;
  }
  const int bh = blockIdx.y;
  const int b = bh / 12, h = bh - b * 12;
  const size_t brow = (size_t)b << 10;
  const int q0 = qt << 6;
  const int tid = threadIdx.x, lane = tid & 63, w = tid >> 6;
  const int l16 = lane & 15, kg = lane >> 4;

  const int c1 = tid, c2 = tid + 256;  // 512 chunks = 64 rows * 8
  const int row1 = c1 >> 3, cc1 = c1 & 7;
  const int row2 = c2 >> 3, cc2 = c2 & 7;
  const int sw1 = ((cc1 ^ (row1 & 7)) << 3);  // K pre-swizzled source elem offset
  const int sw2 = ((cc2 ^ (row2 & 7)) << 3);
  // sigma = 3-bit bit-reverse for V store swizzle
  const int sg1 = ((cc1 & 1) << 2) | (cc1 & 2) | ((cc1 >> 2) & 1);
  const int sg2 = ((cc2 & 1) << 2) | (cc2 & 2) | ((cc2 >> 2) & 1);
  const int vcol1 = row1 ^ (sg1 << 3), d01 = cc1 << 3;
  const int vcol2 = row2 ^ (sg2 << 3), d02 = cc2 << 3;

  const int cbK = 768 + (h << 6), cbV = 1536 + (h << 6);

  // Q fragments direct from global (one-time)
  const u16* Qbase = qkv + (brow + q0 + (w << 4) + l16) * 2304 + (h << 6) + (kg << 3);
  const bf8_t qf0 = *(const bf8_t*)(Qbase);
  const bf8_t qf1 = *(const bf8_t*)(Qbase + 32);

  // prologue: stage K(t0); load V(t0) rows into regs
  gld16(qkv + (brow + (t0 << 6) + row1) * 2304 + cbK + sw1, Ks[t0 & 1] + (size_t)(c1 - lane) * 8);
  gld16(qkv + (brow + (t0 << 6) + row2) * 2304 + cbK + sw2, Ks[t0 & 1] + (size_t)(c2 - lane) * 8);
  bf8_t v1 = *(const bf8_t*)(qkv + (brow + (t0 << 6) + row1) * 2304 + cbV + (cc1 << 3));
  bf8_t v2 = *(const bf8_t*)(qkv + (brow + (t0 << 6) + row2) * 2304 + cbV + (cc2 << 3));

  f32x4 oacc[4];
  const f32x4 fz = {0.f, 0.f, 0.f, 0.f};
#pragma unroll
  for (int dg = 0; dg < 4; dg++) oacc[dg] = fz;
  float mrun[4], lrun[4];
#pragma unroll
  for (int j = 0; j < 4; j++) {
    mrun[j] = -1e30f;
    lrun[j] = 0.f;
  }

  for (int kt = t0; kt < t1; kt++) {
    const int cur = kt & 1;
    u16* Vc = Vt[cur];
    // write staged V regs -> swizzled transposed LDS (conflict-free)
#pragma unroll
    for (int i = 0; i < 8; i++) Vc[(d01 + i) * 64 + vcol1] = (u16)v1[i];
#pragma unroll
    for (int i = 0; i < 8; i++) Vc[(d02 + i) * 64 + vcol2] = (u16)v2[i];
    __syncthreads();  // drains K(kt) gld16, publishes Vt(kt)

    if (kt + 1 < t1) {  // issue next tile's staging; completes under this tile's compute
      const int nr = (kt + 1) << 6;
      gld16(qkv + (brow + nr + row1) * 2304 + cbK + sw1, Ks[cur ^ 1] + (size_t)(c1 - lane) * 8);
      gld16(qkv + (brow + nr + row2) * 2304 + cbK + sw2, Ks[cur ^ 1] + (size_t)(c2 - lane) * 8);
      v1 = *(const bf8_t*)(qkv + (brow + nr + row1) * 2304 + cbV + (cc1 << 3));
      v2 = *(const bf8_t*)(qkv + (brow + nr + row2) * 2304 + cbV + (cc2 << 3));
    }

    const u16* Kc = Ks[cur];
    // QK^T -> sv[g][j]
    float sv[4][4];
#pragma unroll
    for (int g = 0; g < 4; g++) {
      const int key = (g << 4) + l16;
      const int ch0 = kg ^ (key & 7);
      const int ch1 = (kg + 4) ^ (key & 7);
      f32x4 z = fz;
      z = MFMA(qf0, *(const bf8_t*)&Kc[key * 64 + (ch0 << 3)], z);
      z = MFMA(qf1, *(const bf8_t*)&Kc[key * 64 + (ch1 << 3)], z);
      const int gkey = (kt << 6) + key;
#pragma unroll
      for (int j = 0; j < 4; j++) {
        const int grow = q0 + (w << 4) + (kg << 2) + j;
        sv[g][j] = (gkey <= grow) ? z[j] * 0.125f : -1e30f;
      }
    }
    // online softmax (16-lane row groups)
    float tm[4];
#pragma unroll
    for (int j = 0; j < 4; j++)
      tm[j] = fmaxf(fmaxf(sv[0][j], sv[1][j]), fmaxf(sv[2][j], sv[3][j]));
#pragma unroll
    for (int o = 1; o < 16; o <<= 1)
#pragma unroll
      for (int j = 0; j < 4; j++) tm[j] = fmaxf(tm[j], __shfl_xor(tm[j], o, 64));
    float corr[4], tsum[4];
#pragma unroll
    for (int j = 0; j < 4; j++) {
      const float mn = fmaxf(mrun[j], tm[j]);
      corr[j] = __expf(mrun[j] - mn);
      mrun[j] = mn;
      tsum[j] = 0.f;
    }
#pragma unroll
    for (int g = 0; g < 4; g++)
#pragma unroll
      for (int j = 0; j < 4; j++) {
        const float p = __expf(sv[g][j] - mrun[j]);
        sv[g][j] = p;
        tsum[j] += p;
      }
#pragma unroll
    for (int o = 1; o < 16; o <<= 1)
#pragma unroll
      for (int j = 0; j < 4; j++) tsum[j] += __shfl_xor(tsum[j], o, 64);
#pragma unroll
    for (int j = 0; j < 4; j++) lrun[j] = lrun[j] * corr[j] + tsum[j];
#pragma unroll
    for (int dg = 0; dg < 4; dg++)
#pragma unroll
      for (int j = 0; j < 4; j++) oacc[dg][j] *= corr[j];
    // P -> LDS bf16 (C-layout -> A-layout relay, per-wave)
#pragma unroll
    for (int g = 0; g < 4; g++)
#pragma unroll
      for (int j = 0; j < 4; j++)
        Ps[w][((kg << 2) + j) * 72 + (g << 4) + l16] = f2bf(sv[g][j]);
    const bf8_t pf0 = *(const bf8_t*)&Ps[w][l16 * 72 + (kg << 3)];
    const bf8_t pf1 = *(const bf8_t*)&Ps[w][l16 * 72 + (kg << 3) + 32];
    // PV from sigma-swizzled Vt (conflict-free b128 reads)
#pragma unroll
    for (int dg = 0; dg < 4; dg++) {
      const int sgr = (((l16 >> 3) & 1) << 2) | ((dg & 1) << 1) | (dg >> 1);
      const int d = (dg << 4) + l16;
      oacc[dg] = MFMA(pf0, *(const bf8_t*)&Vc[d * 64 + ((kg ^ sgr) << 3)], oacc[dg]);
      oacc[dg] = MFMA(pf1, *(const bf8_t*)&Vc[d * 64 + (((4 + kg) ^ sgr) << 3)], oacc[dg]);
    }
  }

  float inv[4];
#pragma unroll
  for (int j = 0; j < 4; j++) inv[j] = 1.f / lrun[j];
  if constexpr (SPLIT) {
    const int slot = (((bh << 4) + qt) << 2) + c;
    u16* po = part_o + (size_t)slot * 4096;
#pragma unroll
    for (int dg = 0; dg < 4; dg++)
#pragma unroll
      for (int j = 0; j < 4; j++)
        po[((w << 4) + (kg << 2) + j) * 64 + (dg << 4) + l16] = f2bf(oacc[dg][j] * inv[j]);
    if (l16 == 0) {
#pragma unroll
      for (int j = 0; j < 4; j++) {
        const int rr = (w << 4) + (kg << 2) + j;
        partML[(size_t)slot * 128 + rr * 2] = mrun[j];
        partML[(size_t)slot * 128 + rr * 2 + 1] = lrun[j];
      }
    }
  } else {
#pragma unroll
    for (int dg = 0; dg < 4; dg++)
#pragma unroll
      for (int j = 0; j < 4; j++) {
        const size_t grow = brow + q0 + (w << 4) + (kg << 2) + j;
        y[grow * 768 + (h << 6) + (dg << 4) + l16] = f2bf(oacc[dg][j] * inv[j]);
      }
  }
}

// ---------------- combine: merge <=4 normalized chunk partials per (qt, bh) ----------------
__global__ void attn_combine(const u16* __restrict__ part_o, const float* __restrict__ partML,
                             u16* __restrict__ y) {
  const int qt = blockIdx.x, bh = blockIdx.y;
  const int nc = (qt >> 2) + 1;
  const int tid = threadIdx.x;          // 256
  const int r = tid >> 2, cg = tid & 3; // row, 16-col group
  const int b = bh / 12, h = bh - b * 12;
  const int slot0 = ((bh << 4) + qt) << 2;
  float mv0 = -1e30f, mv1 = -1e30f, mv2 = -1e30f, mv3 = -1e30f;
  float lv0 = 0.f, lv1 = 0.f, lv2 = 0.f, lv3 = 0.f;
  mv0 = partML[(size_t)(slot0 + 0) * 128 + r * 2];
  lv0 = partML[(size_t)(slot0 + 0) * 128 + r * 2 + 1];
  if (nc > 1) {
    mv1 = partML[(size_t)(slot0 + 1) * 128 + r * 2];
    lv1 = partML[(size_t)(slot0 + 1) * 128 + r * 2 + 1];
  }
  if (nc > 2) {
    mv2 = partML[(size_t)(slot0 + 2) * 128 + r * 2];
    lv2 = partML[(size_t)(slot0 + 2) * 128 + r * 2 + 1];
  }
  if (nc > 3) {
    mv3 = partML[(size_t)(slot0 + 3) * 128 + r * 2];
    lv3 = partML[(size_t)(slot0 + 3) * 128 + r * 2 + 1];
  }
  const float M = fmaxf(fmaxf(mv0, mv1), fmaxf(mv2, mv3));
  const float w0 = __expf(mv0 - M) * lv0;
  const float w1 = (nc > 1) ? __expf(mv1 - M) * lv1 : 0.f;
  const float w2 = (nc > 2) ? __expf(mv2 - M) * lv2 : 0.f;
  const float w3 = (nc > 3) ? __expf(mv3 - M) * lv3 : 0.f;
  const float invL = 1.f / (w0 + w1 + w2 + w3);
  float acc[16];
#pragma unroll
  for (int i = 0; i < 16; i++) acc[i] = 0.f;
#pragma unroll
  for (int cc = 0; cc < 4; cc++) {
    if (cc < nc) {
      const float wv = (cc == 0) ? w0 : (cc == 1) ? w1 : (cc == 2) ? w2 : w3;
      const bf8_t* op = (const bf8_t*)(part_o + (size_t)(slot0 + cc) * 4096 + r * 64 + (cg << 4));
      const bf8_t o0 = op[0], o1 = op[1];
#pragma unroll
      for (int i = 0; i < 8; i++) {
        acc[i] += wv * b2f((u16)o0[i]);
        acc[8 + i] += wv * b2f((u16)o1[i]);
      }
    }
  }
  u16* yp = y + ((size_t)(b << 10) + (qt << 6) + r) * 768 + (h << 6) + (cg << 4);
#pragma unroll
  for (int i = 0; i < 16; i++) yp[i] = f2bf(acc[i] * invL);
}

// ---------------- launch ----------------
extern "C" void kernel_launch(void* const* d_in, const int* in_sizes, int n_in,
                              void* d_out, int out_size, void* d_ws, size_t ws_size,
                              hipStream_t stream) {
  const float* x = (const float*)d_in[0];
  const float* ln1_g = (const float*)d_in[1];
  const float* ln1_b = (const float*)d_in[2];
  const float* ln2_g = (const float*)d_in[3];
  const float* ln2_b = (const float*)d_in[4];
  const float* w_attn = (const float*)d_in[5];
  const float* b_attn = (const float*)d_in[6];
  const float* w_proj = (const float*)d_in[7];
  const float* b_proj = (const float*)d_in[8];
  const float* w_fc = (const float*)d_in[9];
  const float* b_fc = (const float*)d_in[10];
  const float* w_mlp = (const float*)d_in[11];
  const float* b_mlp = (const float*)d_in[12];
  float* out = (float*)d_out;

  char* ws = (char*)d_ws;
  u16* wqkvT = (u16*)(ws + 0);
  u16* wprojT = (u16*)(ws + 3538944);
  u16* wfcT = (u16*)(ws + 4718592);
  u16* wmlpT = (u16*)(ws + 9437184);
  u16* xn = (u16*)(ws + 14155776);
  u16* qkv = (u16*)(ws + 20447232);
  u16* hbuf = (u16*)(ws + 20447232);  // reuses qkv (dead after attn)
  u16* yb = (u16*)(ws + 45613056);
  float* x1 = (float*)(ws + 51904512);
  float* parts = (float*)(ws + 64487424);   // split-K partials (proj/mlp), 12.58MB each
  u16* part_o = (u16*)(ws + 64487424);      // attn chunk partials (alias; attn-time only)
  float* partML = (float*)(ws + 89653248);  // 3072 slots * 128 floats

  const size_t PSZ = (size_t)4096 * 768 * 4;
  const int nsMlp = (ws_size >= 64487424 + 4 * PSZ) ? 4 : (ws_size >= 64487424 + 2 * PSZ ? 2 : 1);
  const int nsProj = (ws_size >= 64487424 + 2 * PSZ) ? 2 : 1;
  const bool useSplit = ws_size >= 91226112;

  const dim3 wtb(32, 8);
  wtrans_kernel<<<dim3(2304 / 32, 768 / 32), wtb, 0, stream>>>(w_attn, wqkvT, 768, 2304);
  wtrans_kernel<<<dim3(768 / 32, 768 / 32), wtb, 0, stream>>>(w_proj, wprojT, 768, 768);
  wtrans_kernel<<<dim3(3072 / 32, 768 / 32), wtb, 0, stream>>>(w_fc, wfcT, 768, 3072);
  wtrans_kernel<<<dim3(768 / 32, 3072 / 32), wtb, 0, stream>>>(w_mlp, wmlpT, 3072, 768);

  ln_kernel<<<4096, 256, 0, stream>>>(x, ln1_g, ln1_b, xn);
  gemm_kernel<0><<<dim3(18, 32), 256, 0, stream>>>(xn, wqkvT, b_attn, nullptr, qkv,
                                                   4096, 2304, 768, 768);
  if (useSplit) {
    attn_kernel<true><<<dim3(40, 48), 256, 0, stream>>>(qkv, part_o, partML, yb);
    attn_combine<<<dim3(16, 48), 256, 0, stream>>>(part_o, partML, yb);
  } else {
    attn_kernel<false><<<dim3(16, 48), 256, 0, stream>>>(qkv, part_o, partML, yb);
  }

  if (nsProj == 2) {
    gemm_kernel<3><<<dim3(6, 32, 2), 256, 0, stream>>>(yb, wprojT, nullptr, nullptr, parts,
                                                       4096, 768, 768, 384);
    reduce_kernel<<<4096, 192, 0, stream>>>(parts, b_proj, x, x1, 2);
  } else {
    gemm_kernel<2><<<dim3(6, 32), 256, 0, stream>>>(yb, wprojT, b_proj, x, x1,
                                                    4096, 768, 768, 768);
  }

  ln_kernel<<<4096, 256, 0, stream>>>(x1, ln2_g, ln2_b, xn);
  gemm_kernel<1><<<dim3(24, 32), 256, 0, stream>>>(xn, wfcT, b_fc, nullptr, hbuf,
                                                   4096, 3072, 768, 768);

  if (nsMlp > 1) {
    gemm_kernel<3><<<dim3(6, 32, nsMlp), 256, 0, stream>>>(hbuf, wmlpT, nullptr, nullptr, parts,
                                                           4096, 768, 3072, 3072 / nsMlp);
    reduce_kernel<<<4096, 192, 0, stream>>>(parts, b_mlp, x1, out, nsMlp);
  } else {
    gemm_kernel<2><<<dim3(6, 32), 256, 0, stream>>>(hbuf, wmlpT, b_mlp, x1, out,
                                                    4096, 768, 3072, 3072);
  }
}